// Round 14
// baseline (129.850 us; speedup 1.0000x reference)
//
#include <hip/hip_runtime.h>
#include <hip/hip_bf16.h>
#include <math.h>

// Problem constants
#define NTOK 2048
#define CDIM 1024
#define NHEAD 16
#define HDIM 64
// frame id = token >> 8 (8 frames of 256 tokens)

typedef __attribute__((ext_vector_type(8))) short bf16x8;
typedef __attribute__((ext_vector_type(4))) float f32x4;
typedef __attribute__((ext_vector_type(4))) unsigned int u32x4;

// ---------------------------------------------------------------------------
// helpers
// ---------------------------------------------------------------------------
__device__ inline unsigned short bf16_rn(float f) {
    unsigned int u = __float_as_uint(f);
    u += 0x7FFFu + ((u >> 16) & 1u);
    return (unsigned short)(u >> 16);
}

template <int N> __device__ inline void waitcnt_vm() {
    if constexpr (N == 0) asm volatile("s_waitcnt vmcnt(0)" ::: "memory");
    else if constexpr (N == 4) asm volatile("s_waitcnt vmcnt(4)" ::: "memory");
    else if constexpr (N == 6) asm volatile("s_waitcnt vmcnt(6)" ::: "memory");
}

__device__ inline void gload16(const void* g, void* l) {
    __builtin_amdgcn_global_load_lds((const __attribute__((address_space(1))) void*)g,
                                     (__attribute__((address_space(3))) void*)l,
                                     16, 0, 0);
}

// One dispatch: convert x, Wqkv, Wproj to plain bf16.
__global__ __launch_bounds__(256) void conv3(const float* __restrict__ s0, unsigned short* __restrict__ h0, int nb0,
                                             const float* __restrict__ s1, unsigned short* __restrict__ h1, int nb1,
                                             const float* __restrict__ s2, unsigned short* __restrict__ h2) {
    int b = blockIdx.x;
    const float* s;
    unsigned short* hh;
    if (b < nb0) { s = s0; hh = h0; }
    else if (b < nb0 + nb1) { s = s1; hh = h1; b -= nb0; }
    else { s = s2; hh = h2; b -= nb0 + nb1; }
    const int i = b * 256 + threadIdx.x;
    float4 v = ((const float4*)s)[i];
    ushort4 h;
    h.x = bf16_rn(v.x); h.y = bf16_rn(v.y); h.z = bf16_rn(v.z); h.w = bf16_rn(v.w);
    ((ushort4*)hh)[i] = h;
}

// ---------------------------------------------------------------------------
// MFMA GEMM, 1-term bf16, BK=64, counted-vmcnt double buffer. 4 waves (2x2).
// MODE 1 (QKV): epilogue writes attention FRAGMENT-ORDERED bf16 buffers:
//   qf[h][q16][dc][lane][8]   (scaled 0.125)   lane = kg*16 + (tok&15)
//   kf[h][tile][fk][dc][lane][8]
//   vf[h][tile][c][fd][lane][8]
//   q/k go through an LDS transpose (dead staging LDS) -> 16B vector stores.
// MODE 2 (PROJ): f32 out + bias.
// ---------------------------------------------------------------------------
template <int BM, int BN, int M, int N, int K, int MODE>
__global__ __launch_bounds__(256) void gemm_mfma(const unsigned short* __restrict__ Ah,
                                                 const unsigned short* __restrict__ Bh,
                                                 const float* __restrict__ bias,
                                                 float* __restrict__ C,
                                                 unsigned short* __restrict__ qfb,
                                                 unsigned short* __restrict__ kfb,
                                                 unsigned short* __restrict__ vfb) {
    constexpr int BK = 64;
    constexpr int FM = BM / 32;
    constexpr int FN = BN / 32;
    constexpr int ASZ = BM * BK;
    constexpr int BSZ = BN * BK;
    constexpr int BUF = ASZ + BSZ;
    __shared__ unsigned short lds[2 * BUF];

    const int tid = threadIdx.x;
    const int lane = tid & 63;
    const int w = tid >> 6;
    const int m0 = blockIdx.y * BM;
    const int n0 = blockIdx.x * BN;
    const int wave_m = (w >> 1) * (BM / 2);
    const int wave_n = (w & 1) * (BN / 2);
    const int lr = lane & 15;
    const int kg_ = lane >> 4;
    const int srow = tid >> 3;          // 0..31
    const int scol = (tid & 7) * 8;     // bf16 elems within 64-col row

    const size_t aRow = (size_t)(m0 + srow) * K + scol;
    const size_t bRow = (size_t)(n0 + srow) * K + scol;

    f32x4 acc[FM][FN];
#pragma unroll
    for (int i = 0; i < FM; ++i)
#pragma unroll
        for (int j = 0; j < FN; ++j) acc[i][j] = {0.f, 0.f, 0.f, 0.f};

    auto stage = [&](int buf, int k0) {
        unsigned short* bb = lds + buf * BUF;
#pragma unroll
        for (int j = 0; j < BM / 32; ++j)
            gload16(Ah + aRow + (size_t)j * 32 * K + k0, bb + (srow + j * 32) * BK + scol);
#pragma unroll
        for (int j = 0; j < BN / 32; ++j)
            gload16(Bh + bRow + (size_t)j * 32 * K + k0, bb + ASZ + (srow + j * 32) * BK + scol);
    };

    stage(0, 0);
    constexpr int NL = BM / 32 + BN / 32;
    constexpr int NT = K / BK;
    for (int t = 0; t < NT; ++t) {
        const int cur = t & 1;
        if (t + 1 < NT) {
            stage(cur ^ 1, (t + 1) * BK);
            waitcnt_vm<NL>();
        } else {
            waitcnt_vm<0>();
        }
        __builtin_amdgcn_s_barrier();

        const unsigned short* bb = lds + cur * BUF;
        bf16x8 ah[FM][2], bh[FN][2];
#pragma unroll
        for (int f = 0; f < FM; ++f)
#pragma unroll
            for (int ks = 0; ks < 2; ++ks)
                ah[f][ks] = *(const bf16x8*)&bb[(wave_m + f * 16 + lr) * BK + ks * 32 + kg_ * 8];
#pragma unroll
        for (int f = 0; f < FN; ++f)
#pragma unroll
            for (int ks = 0; ks < 2; ++ks)
                bh[f][ks] = *(const bf16x8*)&bb[ASZ + (wave_n + f * 16 + lr) * BK + ks * 32 + kg_ * 8];
        __builtin_amdgcn_s_setprio(1);
#pragma unroll
        for (int ks = 0; ks < 2; ++ks)
#pragma unroll
            for (int fm = 0; fm < FM; ++fm)
#pragma unroll
                for (int fn = 0; fn < FN; ++fn)
                    acc[fm][fn] = __builtin_amdgcn_mfma_f32_16x16x32_bf16(ah[fm][ks], bh[fn][ks], acc[fm][fn], 0, 0, 0);
        __builtin_amdgcn_s_setprio(0);
        asm volatile("" ::: "memory");
        __builtin_amdgcn_s_barrier();
    }

    // epilogue: C/D layout col=lane&15, row=(lane>>4)*4+reg  [m89-verified]
    if constexpr (MODE == 2) {
        float bv[FN];
#pragma unroll
        for (int fn = 0; fn < FN; ++fn) bv[fn] = bias[n0 + wave_n + fn * 16 + lr];
#pragma unroll
        for (int fm = 0; fm < FM; ++fm) {
            const int row0 = m0 + wave_m + fm * 16 + kg_ * 4;
#pragma unroll
            for (int fn = 0; fn < FN; ++fn) {
                const int col = n0 + wave_n + fn * 16 + lr;
#pragma unroll
                for (int r = 0; r < 4; ++r)
                    C[(size_t)(row0 + r) * N + col] = acc[fm][fn][r] + bv[fn];
            }
        }
    } else {
        const int reg = n0 >> 10;  // 0=q, 1=k, 2=v (uniform per block)
        if (reg == 2) {
            // V: direct fragment stores (ushort4, already vectorized)
#pragma unroll
            for (int fn = 0; fn < FN; ++fn) {
                const int col = n0 + wave_n + fn * 16 + lr;
                const int head = (col >> 6) & 15;
                const int d = col & 63;
                const float bv = bias[col];
#pragma unroll
                for (int fm = 0; fm < FM; ++fm) {
                    const int tok = m0 + wave_m + fm * 16 + kg_ * 4;
                    const int tile = tok >> 6;
                    const int t6 = tok & 63;
                    const int c = t6 >> 5;
                    const int t5 = t6 & 31;
                    const int hi = (t5 >> 4) & 1;
                    const int kgv = (t5 >> 2) & 3;
                    const int fd = d >> 4;
                    const int lrv = d & 15;
                    ushort4 pk;
                    pk.x = bf16_rn(acc[fm][fn][0] + bv);
                    pk.y = bf16_rn(acc[fm][fn][1] + bv);
                    pk.z = bf16_rn(acc[fm][fn][2] + bv);
                    pk.w = bf16_rn(acc[fm][fn][3] + bv);
                    const size_t idx = (((size_t)((head * 32 + tile) * 2 + c) * 4 + fd) * 64 +
                                        (kgv * 16 + lrv)) * 8 + hi * 4;
                    *(ushort4*)&vfb[idx] = pk;
                }
            }
        } else {
            // q/k: LDS transpose -> 16B vector stores (LDS is dead post-loop)
            float* sOut = (float*)lds;          // [64][132] f32 = 33.8 KB < 48 KB
            float bv[FN];
#pragma unroll
            for (int fn = 0; fn < FN; ++fn) bv[fn] = bias[n0 + wave_n + fn * 16 + lr];
#pragma unroll
            for (int fm = 0; fm < FM; ++fm) {
                const int row0 = wave_m + fm * 16 + kg_ * 4;
#pragma unroll
                for (int fn = 0; fn < FN; ++fn) {
                    const int col = wave_n + fn * 16 + lr;
#pragma unroll
                    for (int r = 0; r < 4; ++r)
                        sOut[(row0 + r) * 132 + col] = acc[fm][fn][r] + bv[fn];
                }
            }
            __syncthreads();
            const float sc = (reg == 0) ? 0.125f : 1.0f;
            unsigned short* dp = (reg == 0) ? qfb : kfb;
            const int tokL = tid >> 2;        // 0..63
            const int tokG = m0 + tokL;
            const int lrk = tokG & 15;
#pragma unroll
            for (int j = 0; j < 4; ++j) {
                const int ch = (tid & 3) + j * 4;   // 0..15 (8-col chunk)
                const int dcol = ch * 8;
                const int gcol = n0 + dcol;
                const int head = (gcol >> 6) & 15;
                const int d = gcol & 63;
                const int dc = d >> 5;
                const int kgq = (d >> 3) & 3;
                float4 v0 = *(float4*)&sOut[tokL * 132 + dcol];
                float4 v1 = *(float4*)&sOut[tokL * 132 + dcol + 4];
                bf16x8 pk;
                pk[0] = (short)bf16_rn(v0.x * sc);
                pk[1] = (short)bf16_rn(v0.y * sc);
                pk[2] = (short)bf16_rn(v0.z * sc);
                pk[3] = (short)bf16_rn(v0.w * sc);
                pk[4] = (short)bf16_rn(v1.x * sc);
                pk[5] = (short)bf16_rn(v1.y * sc);
                pk[6] = (short)bf16_rn(v1.z * sc);
                pk[7] = (short)bf16_rn(v1.w * sc);
                size_t idx;
                if (reg == 1)
                    idx = (((size_t)((head * 32 + (tokG >> 6)) * 4 + ((tokG >> 4) & 3)) * 2 + dc) * 64 +
                           (kgq * 16 + lrk)) * 8;
                else
                    idx = (((size_t)(head * 128 + (tokG >> 4)) * 2 + dc) * 64 +
                           (kgq * 16 + lrk)) * 8;
                *(bf16x8*)&dp[idx] = pk;
            }
        }
    }
}

// ---------------------------------------------------------------------------
// MFMA sparse flash attention — fragment-ordered global K/V/Q, coalesced
// direct loads, no LDS staging, no barriers in the loop, defer-max (THR=8),
// 2-stage K prefetch (named kA/kB buffers).
// Block = 128 threads = 2 waves = the two KV-halves of one (head, 16-q group).
// ---------------------------------------------------------------------------
__global__ __launch_bounds__(128, 4) void attn_mfma(const unsigned short* __restrict__ qfb,
                                                    const unsigned short* __restrict__ kfb,
                                                    const unsigned short* __restrict__ vfb,
                                                    const float* __restrict__ frame_bias,
                                                    const int* __restrict__ adj,
                                                    const int* __restrict__ is_hub,
                                                    unsigned short* __restrict__ ath) {
    __shared__ float sM[64][18];      // 4.5 KB merge buffer
    __shared__ int sList[32];
    __shared__ float sFB[8];
    __shared__ unsigned long long sHub[32];
    __shared__ int sNT;

    // XCD decode: bid&7 = XCD, each XCD owns heads {2r, 2r+1}
    const int bid = blockIdx.x;
    const int r8 = bid & 7, tt = bid >> 3;      // tt in [0,256)
    const int q16 = tt & 127, hb = tt >> 7;
    const int h = r8 * 2 + hb;
    const int q0 = q16 * 16;

    const int tid = threadIdx.x;    // 0..127
    const int lane = tid & 63;
    const int w = tid >> 6;         // half 0/1
    const int lr = lane & 15;
    const int kg = lane >> 4;
    const int fi = q0 >> 8;

    // ---- Q fragments: 2 coalesced 16B loads ----
    const unsigned short* qb = qfb + ((size_t)(h * 128 + q16) * 2) * 512;
    bf16x8 qh[2];
    qh[0] = *(const bf16x8*)&qb[lane * 8];
    qh[1] = *(const bf16x8*)&qb[512 + lane * 8];
    const bool hq = is_hub[q0 + lr] != 0;

    // ---- prologue tables ----
#pragma unroll
    for (int i = 0; i < 16; ++i) {
        const int t2 = w * 16 + i;
        unsigned long long mb = __ballot(is_hub[t2 * 64 + lane] != 0);
        if (lane == 0) sHub[t2] = mb;
    }
    if (tid < 8) sFB[tid] = frame_bias[fi * 8 + tid];
    if (w == 0) {
        const bool ok = (lane < 32) && (adj[fi * 8 + ((lane & 31) >> 2)] != 0);
        const unsigned long long am = __ballot(ok);
        if (lane == 0) {
            int c = 0;
#pragma unroll 1
            for (int t2 = 0; t2 < 32; ++t2)
                if ((am >> t2) & 1ull) sList[c++] = t2;
            sNT = c;
        }
    }
    __syncthreads();
    const int nt = sNT;   // >= 4 (adj diagonal)

    const unsigned short* kb = kfb + (size_t)(h * 32) * 4096;
    const unsigned short* vb = vfb + (size_t)(h * 32) * 4096;

    float m_i = -INFINITY, l_i = 0.f;
    f32x4 oacc[4];
#pragma unroll
    for (int fd = 0; fd < 4; ++fd) oacc[fd] = {0.f, 0.f, 0.f, 0.f};

    auto loadK = [&](bf16x8 (&kf)[4][2], int tile) {
        const size_t tb = (size_t)tile * 4096 + lane * 8;
#pragma unroll
        for (int fk = 0; fk < 4; ++fk)
#pragma unroll
            for (int dc = 0; dc < 2; ++dc)
                kf[fk][dc] = *(const bf16x8*)&kb[tb + (fk * 2 + dc) * 512];
    };

    auto procTile = [&](int tile, bf16x8 (&kf)[4][2]) {
        const size_t tbase = (size_t)tile * 4096 + lane * 8;
        const int fj = tile >> 2;
        const bool same = (fj == fi);
        const float biasv = sFB[fj];
        const unsigned long long hubmask = sHub[tile];

        // S^T = K . Q^T
        f32x4 sacc[4];
#pragma unroll
        for (int fk = 0; fk < 4; ++fk) sacc[fk] = {0.f, 0.f, 0.f, 0.f};
        __builtin_amdgcn_s_setprio(1);
#pragma unroll
        for (int fk = 0; fk < 4; ++fk)
#pragma unroll
            for (int dc = 0; dc < 2; ++dc)
                sacc[fk] = __builtin_amdgcn_mfma_f32_16x16x32_bf16(kf[fk][dc], qh[dc], sacc[fk], 0, 0, 0);
        __builtin_amdgcn_s_setprio(0);

        // V fragments issued now; softmax VALU hides their latency
        bf16x8 vfr[2][4];
#pragma unroll
        for (int c = 0; c < 2; ++c)
#pragma unroll
            for (int fd = 0; fd < 4; ++fd)
                vfr[c][fd] = *(const bf16x8*)&vb[tbase + (c * 4 + fd) * 512];

        // mask + bias + online softmax with defer-max (THR=8); s in-place
        float s[4][4];
        float rmax = -INFINITY;
#pragma unroll
        for (int fk = 0; fk < 4; ++fk)
#pragma unroll
            for (int r = 0; r < 4; ++r) {
                float val = sacc[fk][r] + biasv;
                if (!same) {
                    const int k = fk * 16 + kg * 4 + r;
                    if (hq || ((hubmask >> k) & 1ull)) val = -INFINITY;
                }
                s[fk][r] = val;
                rmax = fmaxf(rmax, val);
            }
        rmax = fmaxf(rmax, __shfl_xor(rmax, 16));
        rmax = fmaxf(rmax, __shfl_xor(rmax, 32));

        if (!__all(rmax <= m_i + 8.f)) {
            const float mn = fmaxf(m_i, rmax);
            const float alpha = (m_i == -INFINITY) ? 0.f : __expf(m_i - mn);
            m_i = mn;
            l_i *= alpha;
#pragma unroll
            for (int fd = 0; fd < 4; ++fd) {
                oacc[fd][0] *= alpha; oacc[fd][1] *= alpha;
                oacc[fd][2] *= alpha; oacc[fd][3] *= alpha;
            }
        }

        float psum = 0.f;
#pragma unroll
        for (int fk = 0; fk < 4; ++fk)
#pragma unroll
            for (int r = 0; r < 4; ++r) {
                const float pv = (s[fk][r] == -INFINITY) ? 0.f : __expf(s[fk][r] - m_i);
                s[fk][r] = pv;
                psum += pv;
            }
        psum += __shfl_xor(psum, 16);
        psum += __shfl_xor(psum, 32);
        l_i += psum;

        // pack P, O^T += V^T . P^T
        unsigned int pc[4][2];
#pragma unroll
        for (int fk = 0; fk < 4; ++fk)
#pragma unroll
            for (int rp = 0; rp < 2; ++rp)
                pc[fk][rp] = (unsigned int)bf16_rn(s[fk][2 * rp]) |
                             ((unsigned int)bf16_rn(s[fk][2 * rp + 1]) << 16);
        __builtin_amdgcn_s_setprio(1);
#pragma unroll
        for (int c = 0; c < 2; ++c) {
            u32x4 pw = {pc[2 * c][0], pc[2 * c][1], pc[2 * c + 1][0], pc[2 * c + 1][1]};
            bf16x8 pbv = __builtin_bit_cast(bf16x8, pw);
#pragma unroll
            for (int fd = 0; fd < 4; ++fd)
                oacc[fd] = __builtin_amdgcn_mfma_f32_16x16x32_bf16(vfr[c][fd], pbv, oacc[fd], 0, 0, 0);
        }
        __builtin_amdgcn_s_setprio(0);
    };

    // ---- 2-stage K-prefetch loop (tiles w, w+2, w+4, ...) ----
    bf16x8 kA[4][2], kB[4][2];
    loadK(kA, sList[w]);
    int i = w;
    while (true) {
        const int iB = i + 2;
        if (iB < nt) loadK(kB, sList[iB]);
        procTile(sList[i], kA);
        if (iB >= nt) break;
        const int iA2 = i + 4;
        if (iA2 < nt) loadK(kA, sList[iA2]);
        procTile(sList[iB], kB);
        if (iA2 >= nt) break;
        i = iA2;
    }

    // ---- merge the two halves via LDS ----
    if (w == 1) {
        float* mp = &sM[lane][0];
        mp[0] = m_i;
        mp[1] = l_i;
#pragma unroll
        for (int fd = 0; fd < 4; ++fd)
#pragma unroll
            for (int r = 0; r < 4; ++r) mp[2 + fd * 4 + r] = oacc[fd][r];
    }
    __syncthreads();
    if (w == 0) {
        const float mb = sM[lane][0];
        const float lb = sM[lane][1];
        const float m = fmaxf(m_i, mb);
        const float aa = (m_i == -INFINITY) ? 0.f : __expf(m_i - m);
        const float ab = (mb == -INFINITY) ? 0.f : __expf(mb - m);
        const float inv = 1.f / (l_i * aa + lb * ab);
#pragma unroll
        for (int fd = 0; fd < 4; ++fd) {
            ushort4 h4;
            unsigned short hs[4];
#pragma unroll
            for (int r = 0; r < 4; ++r) {
                const float o = (oacc[fd][r] * aa + sM[lane][2 + fd * 4 + r] * ab) * inv;
                hs[r] = bf16_rn(o);
            }
            h4.x = hs[0]; h4.y = hs[1]; h4.z = hs[2]; h4.w = hs[3];
            const size_t idx = (size_t)(q0 + lr) * CDIM + h * 64 + fd * 16 + kg * 4;
            *(ushort4*)&ath[idx] = h4;
        }
    }
}

// ---------------------------------------------------------------------------
extern "C" void kernel_launch(void* const* d_in, const int* in_sizes, int n_in,
                              void* d_out, int out_size, void* d_ws, size_t ws_size,
                              hipStream_t stream) {
    const float* x          = (const float*)d_in[0];
    const float* Wqkv       = (const float*)d_in[1];
    const float* bqkv       = (const float*)d_in[2];
    const float* Wproj      = (const float*)d_in[3];
    const float* bproj      = (const float*)d_in[4];
    const float* frame_bias = (const float*)d_in[5];
    const int*   adj        = (const int*)d_in[6];
    const int*   is_hub     = (const int*)d_in[8];
    float* out = (float*)d_out;

    char* ws = (char*)d_ws;
    size_t off = 0;
    auto alloc_us = [&](size_t n) { unsigned short* p = (unsigned short*)(ws + off); off += n * 2; return p; };
    unsigned short* qfb = alloc_us((size_t)NHEAD * NTOK * HDIM);
    unsigned short* kfb = alloc_us((size_t)NHEAD * NTOK * HDIM);
    unsigned short* vfb = alloc_us((size_t)NHEAD * HDIM * NTOK);
    unsigned short* xh  = alloc_us((size_t)NTOK * CDIM);
    unsigned short* wqh = alloc_us((size_t)3 * CDIM * CDIM);
    unsigned short* wph = alloc_us((size_t)CDIM * CDIM);
    unsigned short* ath = alloc_us((size_t)NTOK * CDIM);

    const int nb_x = (NTOK * CDIM / 4) / 256;
    const int nb_wq = (3 * CDIM * CDIM / 4) / 256;
    const int nb_wp = (CDIM * CDIM / 4) / 256;
    conv3<<<nb_x + nb_wq + nb_wp, 256, 0, stream>>>(x, xh, nb_x,
                                                    Wqkv, wqh, nb_wq,
                                                    Wproj, wph);

    // 1) QKV projection (1-term, BK=64); epilogue emits fragment-ordered bf16
    gemm_mfma<64, 128, NTOK, 3 * CDIM, CDIM, 1>
        <<<dim3((3 * CDIM) / 128, NTOK / 64), 256, 0, stream>>>(
            xh, wqh, bqkv, nullptr, qfb, kfb, vfb);
    // 2) sparse attention (fragment-ordered, barrier-free, defer-max, K-prefetch)
    attn_mfma<<<2048, 128, 0, stream>>>(qfb, kfb, vfb,
                                        frame_bias, adj, is_hub, ath);
    // 3) output projection (1-term, BK=64, BN=64 -> 512 blocks)
    gemm_mfma<64, 64, NTOK, CDIM, CDIM, 2>
        <<<dim3(CDIM / 64, NTOK / 64), 256, 0, stream>>>(
            ath, wph, bproj, out, nullptr, nullptr, nullptr);
}

// Round 15
// 69.505 us; speedup vs baseline: 1.8682x; 1.8682x over previous
//
#include <hip/hip_runtime.h>
#include <hip/hip_bf16.h>
#include <math.h>

// Problem constants
#define NTOK 2048
#define CDIM 1024
#define NHEAD 16
#define HDIM 64
// frame id = token >> 8 (8 frames of 256 tokens)

typedef __attribute__((ext_vector_type(8))) short bf16x8;
typedef __attribute__((ext_vector_type(4))) float f32x4;
typedef __attribute__((ext_vector_type(4))) unsigned int u32x4;

// ---------------------------------------------------------------------------
// helpers
// ---------------------------------------------------------------------------
__device__ inline unsigned short bf16_rn(float f) {
    unsigned int u = __float_as_uint(f);
    u += 0x7FFFu + ((u >> 16) & 1u);
    return (unsigned short)(u >> 16);
}

template <int N> __device__ inline void waitcnt_vm() {
    if constexpr (N == 0) asm volatile("s_waitcnt vmcnt(0)" ::: "memory");
    else if constexpr (N == 4) asm volatile("s_waitcnt vmcnt(4)" ::: "memory");
    else if constexpr (N == 6) asm volatile("s_waitcnt vmcnt(6)" ::: "memory");
}

__device__ inline void gload16(const void* g, void* l) {
    __builtin_amdgcn_global_load_lds((const __attribute__((address_space(1))) void*)g,
                                     (__attribute__((address_space(3))) void*)l,
                                     16, 0, 0);
}

// One dispatch: convert x, Wqkv, Wproj to plain bf16.
__global__ __launch_bounds__(256) void conv3(const float* __restrict__ s0, unsigned short* __restrict__ h0, int nb0,
                                             const float* __restrict__ s1, unsigned short* __restrict__ h1, int nb1,
                                             const float* __restrict__ s2, unsigned short* __restrict__ h2) {
    int b = blockIdx.x;
    const float* s;
    unsigned short* hh;
    if (b < nb0) { s = s0; hh = h0; }
    else if (b < nb0 + nb1) { s = s1; hh = h1; b -= nb0; }
    else { s = s2; hh = h2; b -= nb0 + nb1; }
    const int i = b * 256 + threadIdx.x;
    float4 v = ((const float4*)s)[i];
    ushort4 h;
    h.x = bf16_rn(v.x); h.y = bf16_rn(v.y); h.z = bf16_rn(v.z); h.w = bf16_rn(v.w);
    ((ushort4*)hh)[i] = h;
}

// ---------------------------------------------------------------------------
// MFMA GEMM, 1-term bf16, BK=64, counted-vmcnt double buffer. 4 waves (2x2).
// MODE 1 (QKV): epilogue writes attention FRAGMENT-ORDERED bf16 buffers:
//   qf[h][q16][dc][lane][8]   (scaled 0.125)   lane = kg*16 + (tok&15)
//   kf[h][tile][fk][dc][lane][8]
//   vf[h][tile][c][fd][lane][8]
//   q/k go through an LDS transpose (dead staging LDS) -> 16B vector stores.
// MODE 2 (PROJ): f32 out + bias.
// ---------------------------------------------------------------------------
template <int BM, int BN, int M, int N, int K, int MODE>
__global__ __launch_bounds__(256) void gemm_mfma(const unsigned short* __restrict__ Ah,
                                                 const unsigned short* __restrict__ Bh,
                                                 const float* __restrict__ bias,
                                                 float* __restrict__ C,
                                                 unsigned short* __restrict__ qfb,
                                                 unsigned short* __restrict__ kfb,
                                                 unsigned short* __restrict__ vfb) {
    constexpr int BK = 64;
    constexpr int FM = BM / 32;
    constexpr int FN = BN / 32;
    constexpr int ASZ = BM * BK;
    constexpr int BSZ = BN * BK;
    constexpr int BUF = ASZ + BSZ;
    __shared__ unsigned short lds[2 * BUF];

    const int tid = threadIdx.x;
    const int lane = tid & 63;
    const int w = tid >> 6;
    const int m0 = blockIdx.y * BM;
    const int n0 = blockIdx.x * BN;
    const int wave_m = (w >> 1) * (BM / 2);
    const int wave_n = (w & 1) * (BN / 2);
    const int lr = lane & 15;
    const int kg_ = lane >> 4;
    const int srow = tid >> 3;          // 0..31
    const int scol = (tid & 7) * 8;     // bf16 elems within 64-col row

    const size_t aRow = (size_t)(m0 + srow) * K + scol;
    const size_t bRow = (size_t)(n0 + srow) * K + scol;

    f32x4 acc[FM][FN];
#pragma unroll
    for (int i = 0; i < FM; ++i)
#pragma unroll
        for (int j = 0; j < FN; ++j) acc[i][j] = {0.f, 0.f, 0.f, 0.f};

    auto stage = [&](int buf, int k0) {
        unsigned short* bb = lds + buf * BUF;
#pragma unroll
        for (int j = 0; j < BM / 32; ++j)
            gload16(Ah + aRow + (size_t)j * 32 * K + k0, bb + (srow + j * 32) * BK + scol);
#pragma unroll
        for (int j = 0; j < BN / 32; ++j)
            gload16(Bh + bRow + (size_t)j * 32 * K + k0, bb + ASZ + (srow + j * 32) * BK + scol);
    };

    stage(0, 0);
    constexpr int NL = BM / 32 + BN / 32;
    constexpr int NT = K / BK;
    for (int t = 0; t < NT; ++t) {
        const int cur = t & 1;
        if (t + 1 < NT) {
            stage(cur ^ 1, (t + 1) * BK);
            waitcnt_vm<NL>();
        } else {
            waitcnt_vm<0>();
        }
        __builtin_amdgcn_s_barrier();

        const unsigned short* bb = lds + cur * BUF;
        bf16x8 ah[FM][2], bh[FN][2];
#pragma unroll
        for (int f = 0; f < FM; ++f)
#pragma unroll
            for (int ks = 0; ks < 2; ++ks)
                ah[f][ks] = *(const bf16x8*)&bb[(wave_m + f * 16 + lr) * BK + ks * 32 + kg_ * 8];
#pragma unroll
        for (int f = 0; f < FN; ++f)
#pragma unroll
            for (int ks = 0; ks < 2; ++ks)
                bh[f][ks] = *(const bf16x8*)&bb[ASZ + (wave_n + f * 16 + lr) * BK + ks * 32 + kg_ * 8];
        __builtin_amdgcn_s_setprio(1);
#pragma unroll
        for (int ks = 0; ks < 2; ++ks)
#pragma unroll
            for (int fm = 0; fm < FM; ++fm)
#pragma unroll
                for (int fn = 0; fn < FN; ++fn)
                    acc[fm][fn] = __builtin_amdgcn_mfma_f32_16x16x32_bf16(ah[fm][ks], bh[fn][ks], acc[fm][fn], 0, 0, 0);
        __builtin_amdgcn_s_setprio(0);
        asm volatile("" ::: "memory");
        __builtin_amdgcn_s_barrier();
    }

    // epilogue: C/D layout col=lane&15, row=(lane>>4)*4+reg  [m89-verified]
    if constexpr (MODE == 2) {
        float bv[FN];
#pragma unroll
        for (int fn = 0; fn < FN; ++fn) bv[fn] = bias[n0 + wave_n + fn * 16 + lr];
#pragma unroll
        for (int fm = 0; fm < FM; ++fm) {
            const int row0 = m0 + wave_m + fm * 16 + kg_ * 4;
#pragma unroll
            for (int fn = 0; fn < FN; ++fn) {
                const int col = n0 + wave_n + fn * 16 + lr;
#pragma unroll
                for (int r = 0; r < 4; ++r)
                    C[(size_t)(row0 + r) * N + col] = acc[fm][fn][r] + bv[fn];
            }
        }
    } else {
        const int reg = n0 >> 10;  // 0=q, 1=k, 2=v (uniform per block)
        if (reg == 2) {
            // V: direct fragment stores (ushort4, already vectorized)
#pragma unroll
            for (int fn = 0; fn < FN; ++fn) {
                const int col = n0 + wave_n + fn * 16 + lr;
                const int head = (col >> 6) & 15;
                const int d = col & 63;
                const float bv = bias[col];
#pragma unroll
                for (int fm = 0; fm < FM; ++fm) {
                    const int tok = m0 + wave_m + fm * 16 + kg_ * 4;
                    const int tile = tok >> 6;
                    const int t6 = tok & 63;
                    const int c = t6 >> 5;
                    const int t5 = t6 & 31;
                    const int hi = (t5 >> 4) & 1;
                    const int kgv = (t5 >> 2) & 3;
                    const int fd = d >> 4;
                    const int lrv = d & 15;
                    ushort4 pk;
                    pk.x = bf16_rn(acc[fm][fn][0] + bv);
                    pk.y = bf16_rn(acc[fm][fn][1] + bv);
                    pk.z = bf16_rn(acc[fm][fn][2] + bv);
                    pk.w = bf16_rn(acc[fm][fn][3] + bv);
                    const size_t idx = (((size_t)((head * 32 + tile) * 2 + c) * 4 + fd) * 64 +
                                        (kgv * 16 + lrv)) * 8 + hi * 4;
                    *(ushort4*)&vfb[idx] = pk;
                }
            }
        } else {
            // q/k: LDS transpose -> 16B vector stores (LDS is dead post-loop)
            float* sOut = (float*)lds;          // [64][132] f32 = 33.8 KB < 48 KB
            float bv[FN];
#pragma unroll
            for (int fn = 0; fn < FN; ++fn) bv[fn] = bias[n0 + wave_n + fn * 16 + lr];
#pragma unroll
            for (int fm = 0; fm < FM; ++fm) {
                const int row0 = wave_m + fm * 16 + kg_ * 4;
#pragma unroll
                for (int fn = 0; fn < FN; ++fn) {
                    const int col = wave_n + fn * 16 + lr;
#pragma unroll
                    for (int r = 0; r < 4; ++r)
                        sOut[(row0 + r) * 132 + col] = acc[fm][fn][r] + bv[fn];
                }
            }
            __syncthreads();
            const float sc = (reg == 0) ? 0.125f : 1.0f;
            unsigned short* dp = (reg == 0) ? qfb : kfb;
            const int tokL = tid >> 2;        // 0..63
            const int tokG = m0 + tokL;
            const int lrk = tokG & 15;
#pragma unroll
            for (int j = 0; j < 4; ++j) {
                const int ch = (tid & 3) + j * 4;   // 0..15 (8-col chunk)
                const int dcol = ch * 8;
                const int gcol = n0 + dcol;
                const int head = (gcol >> 6) & 15;
                const int d = gcol & 63;
                const int dc = d >> 5;
                const int kgq = (d >> 3) & 3;
                float4 v0 = *(float4*)&sOut[tokL * 132 + dcol];
                float4 v1 = *(float4*)&sOut[tokL * 132 + dcol + 4];
                bf16x8 pk;
                pk[0] = (short)bf16_rn(v0.x * sc);
                pk[1] = (short)bf16_rn(v0.y * sc);
                pk[2] = (short)bf16_rn(v0.z * sc);
                pk[3] = (short)bf16_rn(v0.w * sc);
                pk[4] = (short)bf16_rn(v1.x * sc);
                pk[5] = (short)bf16_rn(v1.y * sc);
                pk[6] = (short)bf16_rn(v1.z * sc);
                pk[7] = (short)bf16_rn(v1.w * sc);
                size_t idx;
                if (reg == 1)
                    idx = (((size_t)((head * 32 + (tokG >> 6)) * 4 + ((tokG >> 4) & 3)) * 2 + dc) * 64 +
                           (kgq * 16 + lrk)) * 8;
                else
                    idx = (((size_t)(head * 128 + (tokG >> 4)) * 2 + dc) * 64 +
                           (kgq * 16 + lrk)) * 8;
                *(bf16x8*)&dp[idx] = pk;
            }
        }
    }
}

// ---------------------------------------------------------------------------
// MFMA sparse flash attention — round-13 structure (no deep prefetch; the
// round-14 2-stage K prefetch spilled to scratch at the 128-VGPR cap and
// regressed 6x). Fragment-ordered global K/V/Q, coalesced direct loads,
// no LDS staging, no barriers in the loop, defer-max (THR=8).
// Block = 128 threads = 2 waves = the two KV-halves of one (head, 16-q group).
// ---------------------------------------------------------------------------
__global__ __launch_bounds__(128, 4) void attn_mfma(const unsigned short* __restrict__ qfb,
                                                    const unsigned short* __restrict__ kfb,
                                                    const unsigned short* __restrict__ vfb,
                                                    const float* __restrict__ frame_bias,
                                                    const int* __restrict__ adj,
                                                    const int* __restrict__ is_hub,
                                                    unsigned short* __restrict__ ath) {
    __shared__ float sM[64][18];      // 4.5 KB merge buffer
    __shared__ int sList[32];
    __shared__ float sFB[8];
    __shared__ unsigned long long sHub[32];
    __shared__ int sNT;

    // XCD decode: bid&7 = XCD, each XCD owns heads {2r, 2r+1}
    const int bid = blockIdx.x;
    const int r8 = bid & 7, tt = bid >> 3;      // tt in [0,256)
    const int q16 = tt & 127, hb = tt >> 7;
    const int h = r8 * 2 + hb;
    const int q0 = q16 * 16;

    const int tid = threadIdx.x;    // 0..127
    const int lane = tid & 63;
    const int w = tid >> 6;         // half 0/1
    const int lr = lane & 15;
    const int kg = lane >> 4;
    const int fi = q0 >> 8;

    // ---- Q fragments: 2 coalesced 16B loads ----
    const unsigned short* qb = qfb + ((size_t)(h * 128 + q16) * 2) * 512;
    bf16x8 qh[2];
    qh[0] = *(const bf16x8*)&qb[lane * 8];
    qh[1] = *(const bf16x8*)&qb[512 + lane * 8];
    const bool hq = is_hub[q0 + lr] != 0;

    // ---- prologue tables ----
#pragma unroll
    for (int i = 0; i < 16; ++i) {
        const int t2 = w * 16 + i;
        unsigned long long mb = __ballot(is_hub[t2 * 64 + lane] != 0);
        if (lane == 0) sHub[t2] = mb;
    }
    if (tid < 8) sFB[tid] = frame_bias[fi * 8 + tid];
    if (w == 0) {
        const bool ok = (lane < 32) && (adj[fi * 8 + ((lane & 31) >> 2)] != 0);
        const unsigned long long am = __ballot(ok);
        if (lane == 0) {
            int c = 0;
#pragma unroll 1
            for (int t2 = 0; t2 < 32; ++t2)
                if ((am >> t2) & 1ull) sList[c++] = t2;
            sNT = c;
        }
    }
    __syncthreads();
    const int nt = sNT;   // >= 4 (adj diagonal)

    const unsigned short* kb = kfb + (size_t)(h * 32) * 4096;
    const unsigned short* vb = vfb + (size_t)(h * 32) * 4096;

    float m_i = -INFINITY, l_i = 0.f;
    f32x4 oacc[4];
#pragma unroll
    for (int fd = 0; fd < 4; ++fd) oacc[fd] = {0.f, 0.f, 0.f, 0.f};

#pragma unroll 1
    for (int i = w; i < nt; i += 2) {
        const int tile = sList[i];
        const size_t tbase = (size_t)tile * 4096 + lane * 8;
        const int fj = tile >> 2;
        const bool same = (fj == fi);
        const float biasv = sFB[fj];
        const unsigned long long hubmask = sHub[tile];

        // ---- K fragments: 8 coalesced 16B loads ----
        bf16x8 kfr[4][2];
#pragma unroll
        for (int fk = 0; fk < 4; ++fk)
#pragma unroll
            for (int dc = 0; dc < 2; ++dc)
                kfr[fk][dc] = *(const bf16x8*)&kb[tbase + (fk * 2 + dc) * 512];

        // ---- S^T = K . Q^T ----
        f32x4 sacc[4];
#pragma unroll
        for (int fk = 0; fk < 4; ++fk) sacc[fk] = {0.f, 0.f, 0.f, 0.f};
        __builtin_amdgcn_s_setprio(1);
#pragma unroll
        for (int fk = 0; fk < 4; ++fk)
#pragma unroll
            for (int dc = 0; dc < 2; ++dc)
                sacc[fk] = __builtin_amdgcn_mfma_f32_16x16x32_bf16(kfr[fk][dc], qh[dc], sacc[fk], 0, 0, 0);
        __builtin_amdgcn_s_setprio(0);

        // ---- V fragments issued now; softmax VALU hides their latency ----
        bf16x8 vfr[2][4];
#pragma unroll
        for (int c = 0; c < 2; ++c)
#pragma unroll
            for (int fd = 0; fd < 4; ++fd)
                vfr[c][fd] = *(const bf16x8*)&vb[tbase + (c * 4 + fd) * 512];

        // ---- mask + bias + online softmax with defer-max (THR=8) ----
        float sv[4][4];
        float rmax = -INFINITY;
#pragma unroll
        for (int fk = 0; fk < 4; ++fk)
#pragma unroll
            for (int r = 0; r < 4; ++r) {
                float val = sacc[fk][r] + biasv;
                if (!same) {
                    const int k = fk * 16 + kg * 4 + r;
                    if (hq || ((hubmask >> k) & 1ull)) val = -INFINITY;
                }
                sv[fk][r] = val;
                rmax = fmaxf(rmax, val);
            }
        rmax = fmaxf(rmax, __shfl_xor(rmax, 16));
        rmax = fmaxf(rmax, __shfl_xor(rmax, 32));

        if (!__all(rmax <= m_i + 8.f)) {      // rescale only on real max growth
            const float mn = fmaxf(m_i, rmax);
            const float alpha = (m_i == -INFINITY) ? 0.f : __expf(m_i - mn);
            m_i = mn;
            l_i *= alpha;
#pragma unroll
            for (int fd = 0; fd < 4; ++fd) {
                oacc[fd][0] *= alpha; oacc[fd][1] *= alpha;
                oacc[fd][2] *= alpha; oacc[fd][3] *= alpha;
            }
        }

        float p4[4][4];
        float psum = 0.f;
#pragma unroll
        for (int fk = 0; fk < 4; ++fk)
#pragma unroll
            for (int r = 0; r < 4; ++r) {
                const float pv = (sv[fk][r] == -INFINITY) ? 0.f : __expf(sv[fk][r] - m_i);
                p4[fk][r] = pv;
                psum += pv;
            }
        psum += __shfl_xor(psum, 16);
        psum += __shfl_xor(psum, 32);
        l_i += psum;

        // ---- pack P, O^T += V^T . P^T (k-slot permuted to match vf order) ----
        unsigned int pc[4][2];
#pragma unroll
        for (int fk = 0; fk < 4; ++fk)
#pragma unroll
            for (int rp = 0; rp < 2; ++rp)
                pc[fk][rp] = (unsigned int)bf16_rn(p4[fk][2 * rp]) |
                             ((unsigned int)bf16_rn(p4[fk][2 * rp + 1]) << 16);
        __builtin_amdgcn_s_setprio(1);
#pragma unroll
        for (int c = 0; c < 2; ++c) {
            u32x4 pw = {pc[2 * c][0], pc[2 * c][1], pc[2 * c + 1][0], pc[2 * c + 1][1]};
            bf16x8 pbv = __builtin_bit_cast(bf16x8, pw);
#pragma unroll
            for (int fd = 0; fd < 4; ++fd)
                oacc[fd] = __builtin_amdgcn_mfma_f32_16x16x32_bf16(vfr[c][fd], pbv, oacc[fd], 0, 0, 0);
        }
        __builtin_amdgcn_s_setprio(0);
    }

    // ---- merge the two halves via LDS ----
    if (w == 1) {
        float* mp = &sM[lane][0];
        mp[0] = m_i;
        mp[1] = l_i;
#pragma unroll
        for (int fd = 0; fd < 4; ++fd)
#pragma unroll
            for (int r = 0; r < 4; ++r) mp[2 + fd * 4 + r] = oacc[fd][r];
    }
    __syncthreads();
    if (w == 0) {
        const float mb = sM[lane][0];
        const float lb = sM[lane][1];
        const float m = fmaxf(m_i, mb);
        const float aa = (m_i == -INFINITY) ? 0.f : __expf(m_i - m);
        const float ab = (mb == -INFINITY) ? 0.f : __expf(mb - m);
        const float inv = 1.f / (l_i * aa + lb * ab);
#pragma unroll
        for (int fd = 0; fd < 4; ++fd) {
            ushort4 h4;
            unsigned short hs[4];
#pragma unroll
            for (int r = 0; r < 4; ++r) {
                const float o = (oacc[fd][r] * aa + sM[lane][2 + fd * 4 + r] * ab) * inv;
                hs[r] = bf16_rn(o);
            }
            h4.x = hs[0]; h4.y = hs[1]; h4.z = hs[2]; h4.w = hs[3];
            const size_t idx = (size_t)(q0 + lr) * CDIM + h * 64 + fd * 16 + kg * 4;
            *(ushort4*)&ath[idx] = h4;
        }
    }
}

// ---------------------------------------------------------------------------
extern "C" void kernel_launch(void* const* d_in, const int* in_sizes, int n_in,
                              void* d_out, int out_size, void* d_ws, size_t ws_size,
                              hipStream_t stream) {
    const float* x          = (const float*)d_in[0];
    const float* Wqkv       = (const float*)d_in[1];
    const float* bqkv       = (const float*)d_in[2];
    const float* Wproj      = (const float*)d_in[3];
    const float* bproj      = (const float*)d_in[4];
    const float* frame_bias = (const float*)d_in[5];
    const int*   adj        = (const int*)d_in[6];
    const int*   is_hub     = (const int*)d_in[8];
    float* out = (float*)d_out;

    char* ws = (char*)d_ws;
    size_t off = 0;
    auto alloc_us = [&](size_t n) { unsigned short* p = (unsigned short*)(ws + off); off += n * 2; return p; };
    unsigned short* qfb = alloc_us((size_t)NHEAD * NTOK * HDIM);
    unsigned short* kfb = alloc_us((size_t)NHEAD * NTOK * HDIM);
    unsigned short* vfb = alloc_us((size_t)NHEAD * HDIM * NTOK);
    unsigned short* xh  = alloc_us((size_t)NTOK * CDIM);
    unsigned short* wqh = alloc_us((size_t)3 * CDIM * CDIM);
    unsigned short* wph = alloc_us((size_t)CDIM * CDIM);
    unsigned short* ath = alloc_us((size_t)NTOK * CDIM);

    const int nb_x = (NTOK * CDIM / 4) / 256;
    const int nb_wq = (3 * CDIM * CDIM / 4) / 256;
    const int nb_wp = (CDIM * CDIM / 4) / 256;
    conv3<<<nb_x + nb_wq + nb_wp, 256, 0, stream>>>(x, xh, nb_x,
                                                    Wqkv, wqh, nb_wq,
                                                    Wproj, wph);

    // 1) QKV projection (1-term, BK=64); epilogue emits fragment-ordered bf16
    gemm_mfma<64, 128, NTOK, 3 * CDIM, CDIM, 1>
        <<<dim3((3 * CDIM) / 128, NTOK / 64), 256, 0, stream>>>(
            xh, wqh, bqkv, nullptr, qfb, kfb, vfb);
    // 2) sparse attention (fragment-ordered, barrier-free, defer-max)
    attn_mfma<<<2048, 128, 0, stream>>>(qfb, kfb, vfb,
                                        frame_bias, adj, is_hub, ath);
    // 3) output projection (1-term, BK=64, BN=64 -> 512 blocks)
    gemm_mfma<64, 64, NTOK, CDIM, CDIM, 2>
        <<<dim3(CDIM / 64, NTOK / 64), 256, 0, stream>>>(
            ath, wph, bproj, out, nullptr, nullptr, nullptr);
}